// Round 4
// baseline (210.323 us; speedup 1.0000x reference)
//
#include <hip/hip_runtime.h>

#define BN_EPS 1e-5f

// Single fused kernel, one block per batch (grid=16, 1024 threads).
// Dependency cone of the only consumed output position:
//   out(8,8,8) <- x2[15..17]^3 (64ch) <- x1[29..35]^3 (32ch) <- voxel[28..36]^3
// All interior (no padding logic).
//
// Key layouts (all transaction-audited):
//   s_x1: channel-last [343 pos][32 ci]  -> conv2 reads ds_read_b64 at
//         pos*32 + 2j: banks {2j,2j+1} bijective over 16 lanes, identical
//         addresses across the wave's 4 co-groups (broadcast). conv1 writes
//         coalesced (lane = co).
//   w2:   4-chunk coalesced float4 bounce through 55 KB LDS (16 co/chunk),
//         chunk c+1 global loads in flight while chunk c is consumed;
//         chunk 0 flies during conv1. Then per-lane LDS->reg (54 floats).
//   conv2 inner loop: row-register cache (7 x float2 per (z,y) row), i-grouped
//         accumulators p2[9] so only 86 hot VGPRs.
__global__ __launch_bounds__(1024) void backbone_fused_kernel(
    const float* __restrict__ voxel,
    const float* __restrict__ w1, const float* __restrict__ g1,
    const float* __restrict__ b1, const float* __restrict__ m1, const float* __restrict__ v1,
    const float* __restrict__ w2, const float* __restrict__ g2,
    const float* __restrict__ b2, const float* __restrict__ m2, const float* __restrict__ v2,
    const float* __restrict__ w3, const float* __restrict__ g3,
    const float* __restrict__ b3, const float* __restrict__ m3, const float* __restrict__ v3,
    const float* __restrict__ wp, const float* __restrict__ bp,
    float* __restrict__ out)
{
    const int b   = blockIdx.x;
    const int tid = threadIdx.x;

    __shared__ __align__(16) float s_in[729];     // 9^3 input patch
    __shared__ float s_w1[864];                   // 32 x 27
    __shared__ __align__(16) float s_x1[10976];   // [343][32] channel-last
    __shared__ __align__(16) float s_wb[13824];   // w2 chunk bounce: [16co][32ci][27]
    __shared__ __align__(16) float s_x2[1728];    // [64 co][27]
    __shared__ float s_x3[128];
    __shared__ __align__(16) float s_fc[1024];
    __shared__ float sa1[32], ss1[32];
    __shared__ float sa2[64], ss2[64];
    __shared__ float sa3[128], ss3[128];

    // ---- Phase 0: stage input patch + conv1 weights + BN consts;
    //      issue w2 chunk-0 global loads (consumed after conv1) ----
    const float* vb = voxel + (size_t)b * 262144;
    if (tid < 729) {
        int z = tid / 81, r = tid % 81, y = r / 9, x = r % 9;
        s_in[tid] = vb[(28 + z) * 4096 + (28 + y) * 64 + (28 + x)];
    }
    if (tid < 864) s_w1[tid] = w1[tid];
    if (tid >= 896) {                       // 128 ch of stage 3
        int c = tid - 896;
        float a = g3[c] * rsqrtf(v3[c] + BN_EPS);
        sa3[c] = a; ss3[c] = b3[c] - m3[c] * a;
    } else if (tid >= 832) {                // 64 ch of stage 2
        int c = tid - 832;
        float a = g2[c] * rsqrtf(v2[c] + BN_EPS);
        sa2[c] = a; ss2[c] = b2[c] - m2[c] * a;
    } else if (tid >= 800) {                // 32 ch of stage 1
        int c = tid - 800;
        float a = g1[c] * rsqrtf(v1[c] + BN_EPS);
        sa1[c] = a; ss1[c] = b1[c] - m1[c] * a;
    }

    // w2 chunk 0 -> regs (coalesced float4; 3456 float4 per chunk, 864 loaders)
    const float4* w2v = (const float4*)w2;
    float4 wrg0, wrg1, wrg2, wrg3;
    if (tid < 864) {
        wrg0 = w2v[tid];
        wrg1 = w2v[864 + tid];
        wrg2 = w2v[1728 + tid];
        wrg3 = w2v[2592 + tid];
    }
    __syncthreads();

    // ---- Phase 1: conv1 (stride 1) + BN + ReLU -> s_x1[pos][co] ----
    {
        const int co = tid & 31;            // constant across iterations
        float wc[27];
        #pragma unroll
        for (int k = 0; k < 27; ++k) wc[k] = s_w1[co * 27 + k];
        const float a = sa1[co], sh = ss1[co];
        for (int it = 0; it < 11; ++it) {
            int t = it * 1024 + tid;
            if (t < 10976) {
                int r = t >> 5;             // position 0..342
                int z = r / 49, rem = r % 49, y = rem / 7, x = rem % 7;
                float acc = 0.f;
                #pragma unroll
                for (int kd = 0; kd < 3; ++kd)
                #pragma unroll
                for (int kh = 0; kh < 3; ++kh)
                #pragma unroll
                for (int kw = 0; kw < 3; ++kw)
                    acc += s_in[(z + kd) * 81 + (y + kh) * 9 + (x + kw)]
                         * wc[kd * 9 + kh * 3 + kw];
                s_x1[t] = fmaxf(acc * a + sh, 0.f);   // t = pos*32 + co
            }
        }
    }

    // ---- Phase 1.5: w2 chunk dance -> per-lane weight regs wr2[27] ----
    const int co = tid >> 4;        // 0..63 output channel (conv2)
    const int j  = tid & 15;        // ci-pair index (ci = 2j, 2j+1)
    const int myck = co >> 4;       // which chunk holds my weights
    float2 wr2[27];
    #pragma unroll
    for (int c = 0; c < 4; ++c) {
        __syncthreads();            // prev chunk consumed (c=0: conv1 done)
        if (tid < 864) {            // write staged chunk c (coalesced b128)
            float4* wbv = (float4*)s_wb;
            wbv[tid]        = wrg0;
            wbv[864 + tid]  = wrg1;
            wbv[1728 + tid] = wrg2;
            wbv[2592 + tid] = wrg3;
        }
        __syncthreads();
        if (c < 3 && tid < 864) {   // issue chunk c+1 (flies during reads)
            wrg0 = w2v[(c + 1) * 3456 + tid];
            wrg1 = w2v[(c + 1) * 3456 + 864 + tid];
            wrg2 = w2v[(c + 1) * 3456 + 1728 + tid];
            wrg3 = w2v[(c + 1) * 3456 + 2592 + tid];
        }
        if (myck == c) {
            const float* wb = s_wb + ((co & 15) * 32 + 2 * j) * 27;
            #pragma unroll
            for (int k = 0; k < 27; ++k) {
                wr2[k].x = wb[k];        // ci = 2j
                wr2[k].y = wb[27 + k];   // ci = 2j+1
            }
        }
    }

    // ---- Phase 2: conv2 (stride 2) + BN + ReLU -> s_x2[co][27] ----
    {
        const float a2 = sa2[co], sh2 = ss2[co];
        #pragma unroll
        for (int i = 0; i < 3; ++i) {       // output z-position group
            float2 p2[9];
            #pragma unroll
            for (int q = 0; q < 9; ++q) { p2[q].x = 0.f; p2[q].y = 0.f; }
            #pragma unroll
            for (int kd = 0; kd < 3; ++kd) {
                const int z = 2 * i + kd;   // x1 z-plane
                #pragma unroll
                for (int y = 0; y < 7; ++y) {
                    float2 row[7];          // x-row cache for (z,y)
                    #pragma unroll
                    for (int x = 0; x < 7; ++x)
                        row[x] = *(const float2*)&s_x1[((z * 7 + y) * 7 + x) * 32 + 2 * j];
                    #pragma unroll
                    for (int jj = 0; jj < 3; ++jj) {
                        const int kh = y - 2 * jj;
                        if (kh >= 0 && kh < 3) {
                            #pragma unroll
                            for (int k = 0; k < 3; ++k)
                            #pragma unroll
                            for (int kw = 0; kw < 3; ++kw) {
                                const float2 w = wr2[kd * 9 + kh * 3 + kw];
                                const float2 xv = row[2 * k + kw];
                                p2[jj * 3 + k].x += xv.x * w.x;
                                p2[jj * 3 + k].y += xv.y * w.y;
                            }
                        }
                    }
                }
            }
            // reduce over 2 ci components + 16 lanes -> lane j==0 writes
            #pragma unroll
            for (int q = 0; q < 9; ++q) {
                float s = p2[q].x + p2[q].y;
                s += __shfl_xor(s, 1);
                s += __shfl_xor(s, 2);
                s += __shfl_xor(s, 4);
                s += __shfl_xor(s, 8);
                if (j == 0)
                    s_x2[co * 27 + i * 9 + q] = fmaxf(s * a2 + sh2, 0.f);
            }
        }
    }
    __syncthreads();

    // ---- Phase 3: conv3 center + BN + ReLU -> s_x3[128] ----
    {
        const float4* xv4 = (const float4*)s_x2;   // 432 float4
        #pragma unroll
        for (int cc = 0; cc < 2; ++cc) {
            const int co3 = co + 64 * cc;          // co = tid>>4 reused as group
            const float4* wv = (const float4*)(w3 + (size_t)co3 * 1728);
            float acc = 0.f;
            #pragma unroll
            for (int t = 0; t < 27; ++t) {
                float4 w4 = wv[j + 16 * t];
                float4 x4 = xv4[j + 16 * t];
                acc += w4.x * x4.x + w4.y * x4.y + w4.z * x4.z + w4.w * x4.w;
            }
            acc += __shfl_xor(acc, 1);
            acc += __shfl_xor(acc, 2);
            acc += __shfl_xor(acc, 4);
            acc += __shfl_xor(acc, 8);
            if (j == 0)
                s_x3[co3] = fmaxf(acc * sa3[co3] + ss3[co3], 0.f);
        }
    }
    __syncthreads();

    // ---- Phase 4: FC, coalesced over features, 4-way ci split ----
    {
        const int q = tid >> 8;       // 0..3
        const int f = tid & 255;
        float acc = 0.f;
        #pragma unroll
        for (int c = 0; c < 32; ++c) {
            int ci = q * 32 + c;
            acc += s_x3[ci] * wp[ci * 256 + f];
        }
        s_fc[q * 256 + f] = acc;
    }
    __syncthreads();
    if (tid < 256) {
        out[b * 256 + tid] = bp[tid] + s_fc[tid] + s_fc[256 + tid]
                           + s_fc[512 + tid] + s_fc[768 + tid];
    }
}

extern "C" void kernel_launch(void* const* d_in, const int* in_sizes, int n_in,
                              void* d_out, int out_size, void* d_ws, size_t ws_size,
                              hipStream_t stream) {
    const float* voxel = (const float*)d_in[0];
    const float* w1 = (const float*)d_in[1];
    const float* g1 = (const float*)d_in[2];
    const float* b1 = (const float*)d_in[3];
    const float* m1 = (const float*)d_in[4];
    const float* v1 = (const float*)d_in[5];
    const float* w2 = (const float*)d_in[6];
    const float* g2 = (const float*)d_in[7];
    const float* b2 = (const float*)d_in[8];
    const float* m2 = (const float*)d_in[9];
    const float* v2 = (const float*)d_in[10];
    const float* w3 = (const float*)d_in[11];
    const float* g3 = (const float*)d_in[12];
    const float* b3 = (const float*)d_in[13];
    const float* m3 = (const float*)d_in[14];
    const float* v3 = (const float*)d_in[15];
    const float* wp = (const float*)d_in[16];
    const float* bp = (const float*)d_in[17];
    float* out = (float*)d_out;

    backbone_fused_kernel<<<16, 1024, 0, stream>>>(
        voxel, w1, g1, b1, m1, v1, w2, g2, b2, m2, v2,
        w3, g3, b3, m3, v3, wp, bp, out);
}